// Round 10
// baseline (464.009 us; speedup 1.0000x reference)
//
#include <hip/hip_runtime.h>
#include <hip/hip_cooperative_groups.h>
namespace cg = cooperative_groups;

typedef __bf16 bf16;
typedef __bf16 bf16x8 __attribute__((ext_vector_type(8)));
typedef float f32x4 __attribute__((ext_vector_type(4)));

#define KDIM    192                     // E + 2H
#define RDIM    320                     // 3H + 2H
#define A_PAD   200                     // padded A-row stride (bf16 elems)
#define LOG2E   1.4426950408889634f

__device__ __forceinline__ float rcpf(float x) { return __builtin_amdgcn_rcpf(x); }
__device__ __forceinline__ float sig2(float p)  { return rcpf(1.f + exp2f(-p)); }
__device__ __forceinline__ float tanhf_(float x){ return 2.f * rcpf(1.f + exp2f(-2.f * LOG2E * x)) - 1.f; }

__device__ __forceinline__ void gates(const f32x4* acc,
        const float4& bI, const float4& bO, const float4& bU,
        const float4& bL, const float4& bR,
        const float4& cl, const float4& cr, float4& c4, float4& h4) {
    const float* pbI = &bI.x; const float* pbO = &bO.x; const float* pbU = &bU.x;
    const float* pbL = &bL.x; const float* pbR = &bR.x;
    const float* pcl = &cl.x; const float* pcr = &cr.x;
    float* pc4 = &c4.x; float* ph4 = &h4.x;
#pragma unroll
    for (int r = 0; r < 4; r++) {
        float i_g = sig2(acc[0][r] + pbI[r]);
        float o_g = sig2(acc[1][r] + pbO[r]);
        float u_g = tanhf_(sig2(acc[2][r] + pbU[r]));   // ref: tanh(sigmoid(pre_u))
        float fl  = sig2(acc[3][r] + pbL[r]);
        float fr  = sig2(acc[4][r] + pbR[r]);
        float c = i_g * u_g + fl * pcl[r] + fr * pcr[r];
        pc4[r] = c;
        ph4[r] = o_g * tanhf_(c);
    }
}

// NT consecutive 16-node tiles of one level; W fragments reused across NT tiles.
template<int NT>
__device__ __forceinline__ void do_tiles(
        int m, int s, int o, int topLeaf, int isBot,
        const bf16* Acur, bf16* Anx,
        const bf16* __restrict__ Wcat, const int* __restrict__ token_ids,
        const float* __restrict__ leafC,
        bf16* __restrict__ H, float* __restrict__ c_buf,
        int l15, int quad, int jw, int jb,
        const float4& bI, const float4& bO, const float4& bU,
        const float4& bL, const float4& bR)
{
    int idx0[NT], idx[NT], gn[NT];
#pragma unroll
    for (int t = 0; t < NT; t++) {
        idx0[t] = t * 16 + l15;
        idx[t] = idx0[t] < m ? idx0[t] : m - 1;
        gn[t] = s + o + idx[t];
    }
    f32x4 acc[NT][5];
#pragma unroll
    for (int t = 0; t < NT; t++)
#pragma unroll
        for (int g = 0; g < 5; g++) acc[t][g] = (f32x4){0.f, 0.f, 0.f, 0.f};

#pragma unroll
    for (int kb = 0; kb < 6; kb++) {
        bf16x8 wf[5];
#pragma unroll
        for (int g = 0; g < 5; g++)
            wf[g] = *(const bf16x8*)(Wcat + (g * 64 + jw + l15) * KDIM + kb * 32 + quad * 8);
        bf16x8 nf[NT];
#pragma unroll
        for (int t = 0; t < NT; t++)
            nf[t] = *(const bf16x8*)(&Acur[idx[t] * A_PAD + kb * 32 + quad * 8]);
#pragma unroll
        for (int t = 0; t < NT; t++)
#pragma unroll
            for (int g = 0; g < 5; g++)
                acc[t][g] = __builtin_amdgcn_mfma_f32_16x16x32_bf16(wf[g], nf[t], acc[t][g], 0, 0, 0);
    }
    float4 cl[NT], cr[NT];
#pragma unroll
    for (int t = 0; t < NT; t++) {
        if (topLeaf) {
            int tkl = token_ids[2 * gn[t] + 1], tkr = token_ids[2 * gn[t] + 2];
            cl[t] = *(const float4*)(leafC + (size_t)tkl * 64 + jb);
            cr[t] = *(const float4*)(leafC + (size_t)tkr * 64 + jb);
        } else {
            cl[t] = *(const float4*)(c_buf + (size_t)(2 * gn[t] + 1) * 64 + jb);
            cr[t] = *(const float4*)(c_buf + (size_t)(2 * gn[t] + 2) * 64 + jb);
        }
    }
#pragma unroll
    for (int t = 0; t < NT; t++) {
        float4 c4, h4;
        gates(acc[t], bI, bO, bU, bL, bR, cl[t], cr[t], c4, h4);
        if (idx0[t] < m) {
            union { bf16 h[4]; uint2 u; } hp;
            const float* ph4 = &h4.x;
#pragma unroll
            for (int r = 0; r < 4; r++) hp.h[r] = (bf16)ph4[r];
            *(float4*)(c_buf + (size_t)gn[t] * 64 + jb) = c4;
            if (!isBot)
                *(uint2*)(&Anx[(idx[t] >> 1) * A_PAD + 64 + (idx[t] & 1) * 64 + jb]) = hp.u;
            else
                *(uint2*)(H + (size_t)gn[t] * 64 + jb) = hp.u;
        }
    }
}

// one depth-7 subtree (levels top..top-6, 64 top nodes); h in LDS ping-pong,
// c via c_buf (L2, same-block barrier visibility).
__device__ void subtree_body(int top, int sub, int leafMode,
        bf16* A0, bf16* A1,
        const bf16* __restrict__ Wcat, const float* __restrict__ bias,
        const bf16* __restrict__ emb16, const int* __restrict__ token_ids,
        const bf16* __restrict__ leafH, const float* __restrict__ leafC,
        bf16* __restrict__ H, float* __restrict__ c_buf, int tid)
{
    const int wave = tid >> 6, lane = tid & 63;
    const int l15 = lane & 15, quad = lane >> 4;
    const int jw = wave * 16, jb = jw + quad * 4;
    const int bot = top - 6;
    const int stop = (1 << top) - 1;
    const float4 bI = *(const float4*)(bias + jb);
    const float4 bO = *(const float4*)(bias + 64 + jb);
    const float4 bU = *(const float4*)(bias + 128 + jb);
    const float4 bL = *(const float4*)(bias + 192 + jb);
    const float4 bR = *(const float4*)(bias + 256 + jb);

    for (int ch = tid; ch < 64 * 8; ch += 256) {
        int row = ch >> 3, k8 = (ch & 7) << 3;
        int tok = token_ids[stop + sub * 64 + row];
        *(uint4*)&A0[row * A_PAD + k8] = *(const uint4*)(emb16 + tok * 64 + k8);
    }
    if (leafMode) {
        for (int ch = tid; ch < 64 * 16; ch += 256) {
            int row = ch >> 4, half = (ch >> 3) & 1, k8 = (ch & 7) << 3;
            int tok = token_ids[2 * (stop + sub * 64 + row) + 1 + half];
            *(uint4*)&A0[row * A_PAD + 64 + half * 64 + k8] =
                *(const uint4*)(leafH + (size_t)tok * 64 + k8);
        }
    } else {
        for (int ch = tid; ch < 64 * 16; ch += 256) {
            int row = ch >> 4, k8 = (ch & 15) << 3;
            int gnc = stop + sub * 64 + row;
            *(uint4*)&A0[row * A_PAD + 64 + k8] =
                *(const uint4*)(H + (size_t)(2 * gnc + 1) * 64 + k8);
        }
    }
    __syncthreads();

    bf16 *Acur = A0, *Anx = A1;
    for (int l = top; l >= bot; l--) {
        const int m = 1 << (l - bot);
        const int s = (1 << l) - 1, o = sub * m;
        const int numT = (m + 15) >> 4;
        const int topLeaf = (l == top) && leafMode;
        const int isBot = (l == bot);
        if (numT == 4)
            do_tiles<4>(m, s, o, topLeaf, isBot, Acur, Anx, Wcat, token_ids, leafC,
                        H, c_buf, l15, quad, jw, jb, bI, bO, bU, bL, bR);
        else if (numT == 2)
            do_tiles<2>(m, s, o, topLeaf, isBot, Acur, Anx, Wcat, token_ids, leafC,
                        H, c_buf, l15, quad, jw, jb, bI, bO, bU, bL, bR);
        else
            do_tiles<1>(m, s, o, topLeaf, isBot, Acur, Anx, Wcat, token_ids, leafC,
                        H, c_buf, l15, quad, jw, jb, bI, bO, bU, bL, bR);
        if (!isBot) {
            int mn = m >> 1, sn = (1 << (l - 1)) - 1, on = sub * mn;
            for (int ch = tid; ch < mn * 8; ch += 256) {
                int row = ch >> 3, k8 = (ch & 7) << 3;
                int tok = token_ids[sn + on + row];
                *(uint4*)&Anx[row * A_PAD + k8] = *(const uint4*)(emb16 + tok * 64 + k8);
            }
        }
        __syncthreads();
        bf16* ta = Acur; Acur = Anx; Anx = ta;
    }
}

// final 3 levels (7 nodes); W from L2; callable from block 0 of mega or tail3.
__device__ void top3_body(
        const bf16* __restrict__ Wcat, const float* __restrict__ bias,
        const bf16* __restrict__ emb16, const int* __restrict__ token_ids,
        bf16* __restrict__ H, float* __restrict__ c_buf, float* __restrict__ out, int tid)
{
    const int wave = tid >> 6, lane = tid & 63;
    const int l15 = lane & 15, quad = lane >> 4;
    const int jw = wave * 16, jb = jw + quad * 4;
    const float4 bI = *(const float4*)(bias + jb);
    const float4 bO = *(const float4*)(bias + 64 + jb);
    const float4 bU = *(const float4*)(bias + 128 + jb);
    const float4 bL = *(const float4*)(bias + 192 + jb);
    const float4 bR = *(const float4*)(bias + 256 + jb);
    for (int l = 2; l >= 0; l--) {
        const int n = 1 << l, start = n - 1;
        int idx = l15 < n ? l15 : n - 1;
        int gn = start + idx;
        int tok = token_ids[gn];
        const bf16* hsrc = H + (size_t)(2 * gn + 1) * 64;
        float4 cl = *(const float4*)(c_buf + (size_t)(2 * gn + 1) * 64 + jb);
        float4 cr = *(const float4*)(c_buf + (size_t)(2 * gn + 2) * 64 + jb);
        bf16x8 nf[6];
        nf[0] = *(const bf16x8*)(emb16 + tok * 64 + quad * 8);
        nf[1] = *(const bf16x8*)(emb16 + tok * 64 + 32 + quad * 8);
#pragma unroll
        for (int kb = 2; kb < 6; kb++)
            nf[kb] = *(const bf16x8*)(hsrc + (kb - 2) * 32 + quad * 8);
        f32x4 acc[5];
#pragma unroll
        for (int g = 0; g < 5; g++) acc[g] = (f32x4){0.f, 0.f, 0.f, 0.f};
#pragma unroll
        for (int kb = 0; kb < 6; kb++)
#pragma unroll
            for (int g = 0; g < 5; g++) {
                bf16x8 wf = *(const bf16x8*)(Wcat + (g * 64 + jw + l15) * KDIM + kb * 32 + quad * 8);
                acc[g] = __builtin_amdgcn_mfma_f32_16x16x32_bf16(wf, nf[kb], acc[g], 0, 0, 0);
            }
        float4 c4, h4;
        gates(acc, bI, bO, bU, bL, bR, cl, cr, c4, h4);
        if (l15 < n) {
            if (l > 0) {
                union { bf16 h[4]; uint2 u; } hp;
                const float* ph4 = &h4.x;
#pragma unroll
                for (int r = 0; r < 4; r++) hp.h[r] = (bf16)ph4[r];
                *(float4*)(c_buf + (size_t)gn * 64 + jb) = c4;
                *(uint2*)(H + (size_t)gn * 64 + jb) = hp.u;
            } else {
                *(float4*)(out + jb) = h4;
                *(float4*)(out + 64 + jb) = c4;
            }
        }
        __syncthreads();
    }
}

// ---- standalone prep (fallback dispatch 1): blocks 0..511 pack, 512..543 leaf tables ----
__global__ void prep_all(const float* __restrict__ emb,
                     const float* __restrict__ W_iou, const float* __restrict__ U_iou,
                     const float* __restrict__ W_f,   const float* __restrict__ U_f,
                     const float* __restrict__ b_Wiou, const float* __restrict__ b_Uiou,
                     const float* __restrict__ b_Wf,   const float* __restrict__ b_Uf,
                     bf16* __restrict__ Wcat, float* __restrict__ bias, bf16* __restrict__ emb16,
                     bf16* __restrict__ leafH, float* __restrict__ leafC) {
    __shared__ __align__(16) bf16 Wl[192 * 72];
    __shared__ __align__(16) bf16 Al[64 * 72];
    const int blk = blockIdx.x, tid = threadIdx.x;
    if (blk < 512) {
        int t = blk * 256 + tid;
        emb16[t] = (bf16)emb[t];
        if (t < RDIM * KDIM) {
            int r = t / KDIM, k = t % KDIM;
            float v;
            if (r < 192) v = (k < 64) ? W_iou[r * 64 + k] : U_iou[r * 128 + (k - 64)];
            else { int rr = r - 192; v = (k < 64) ? W_f[rr * 64 + k] : U_f[rr * 128 + (k - 64)]; }
            Wcat[t] = (bf16)(v * LOG2E);
        }
        if (t < RDIM)
            bias[t] = ((t < 192) ? (b_Wiou[t] + b_Uiou[t]) : (b_Wf[t - 192] + b_Uf[t - 192])) * LOG2E;
        return;
    }
    const int v0 = (blk - 512) * 64;
    for (int i = tid; i < 192 * 64; i += 256) {
        int r = i >> 6, k = i & 63;
        Wl[r * 72 + k] = (bf16)(W_iou[i] * LOG2E);
    }
    for (int i = tid; i < 64 * 64; i += 256) {
        int r = i >> 6, k = i & 63;
        Al[r * 72 + k] = (bf16)emb[(v0 << 6) + i];
    }
    __syncthreads();
    const int wave = tid >> 6, lane = tid & 63;
    const int l15 = lane & 15, quad = lane >> 4;
    const int jw = (wave & 3) * 16, jb = jw + quad * 4;
    f32x4 acc[4][3];
#pragma unroll
    for (int t = 0; t < 4; t++)
#pragma unroll
        for (int g = 0; g < 3; g++) acc[t][g] = (f32x4){0.f, 0.f, 0.f, 0.f};
#pragma unroll
    for (int kb = 0; kb < 2; kb++) {
        bf16x8 wfrag[3], nfrag[4];
#pragma unroll
        for (int g = 0; g < 3; g++)
            wfrag[g] = *(const bf16x8*)(&Wl[(g * 64 + jw + l15) * 72 + kb * 32 + quad * 8]);
#pragma unroll
        for (int t = 0; t < 4; t++)
            nfrag[t] = *(const bf16x8*)(&Al[(t * 16 + l15) * 72 + kb * 32 + quad * 8]);
#pragma unroll
        for (int t = 0; t < 4; t++)
#pragma unroll
            for (int g = 0; g < 3; g++)
                acc[t][g] = __builtin_amdgcn_mfma_f32_16x16x32_bf16(wfrag[g], nfrag[t], acc[t][g], 0, 0, 0);
    }
    float4 bW, bU_;
    bW = *(const float4*)(b_Wiou + jb);       bU_ = *(const float4*)(b_Uiou + jb);
    float4 bI = make_float4((bW.x + bU_.x) * LOG2E, (bW.y + bU_.y) * LOG2E, (bW.z + bU_.z) * LOG2E, (bW.w + bU_.w) * LOG2E);
    bW = *(const float4*)(b_Wiou + 64 + jb);  bU_ = *(const float4*)(b_Uiou + 64 + jb);
    float4 bO = make_float4((bW.x + bU_.x) * LOG2E, (bW.y + bU_.y) * LOG2E, (bW.z + bU_.z) * LOG2E, (bW.w + bU_.w) * LOG2E);
    bW = *(const float4*)(b_Wiou + 128 + jb); bU_ = *(const float4*)(b_Uiou + 128 + jb);
    float4 bU = make_float4((bW.x + bU_.x) * LOG2E, (bW.y + bU_.y) * LOG2E, (bW.z + bU_.z) * LOG2E, (bW.w + bU_.w) * LOG2E);
    const float* pbI = &bI.x; const float* pbO = &bO.x; const float* pbU = &bU.x;
#pragma unroll
    for (int t = 0; t < 4; t++) {
        int v = v0 + t * 16 + l15;
        float4 c4; float* pc4 = &c4.x;
        union { bf16 h[4]; uint2 u; } hp;
#pragma unroll
        for (int r = 0; r < 4; r++) {
            float i_g = sig2(acc[t][0][r] + pbI[r]);
            float o_g = sig2(acc[t][1][r] + pbO[r]);
            float u_g = tanhf_(sig2(acc[t][2][r] + pbU[r]));
            float c = i_g * u_g;
            pc4[r] = c;
            hp.h[r] = (bf16)(o_g * tanhf_(c));
        }
        *(float4*)(leafC + (size_t)v * 64 + jb) = c4;
        *(uint2*)(leafH + (size_t)v * 64 + jb) = hp.u;
    }
}

// ---- fallback subtree kernel (reps subtrees per block) ----
__global__ void __launch_bounds__(256, 2) subtree_kernel(
        const bf16* __restrict__ Wcat, const float* __restrict__ bias,
        const bf16* __restrict__ emb16, const int* __restrict__ token_ids,
        const bf16* __restrict__ leafH, const float* __restrict__ leafC,
        bf16* __restrict__ H, float* __restrict__ c_buf,
        int top, int leafMode, int reps) {
    __shared__ __align__(16) bf16 A0[64 * A_PAD];
    __shared__ __align__(16) bf16 A1[32 * A_PAD];
    for (int rep = 0; rep < reps; rep++)
        subtree_body(top, blockIdx.x * reps + rep, leafMode, A0, A1,
                     Wcat, bias, emb16, token_ids, leafH, leafC, H, c_buf, threadIdx.x);
}

__global__ void __launch_bounds__(256) tail3(
        const bf16* __restrict__ Wcat, const float* __restrict__ bias,
        const bf16* __restrict__ emb16, const int* __restrict__ token_ids,
        bf16* __restrict__ H, float* __restrict__ c_buf, float* __restrict__ out) {
    top3_body(Wcat, bias, emb16, token_ids, H, c_buf, out, threadIdx.x);
}

// ---- cooperative single-kernel path ----
__global__ void __launch_bounds__(256, 2) mega(
        const int* __restrict__ token_ids, const float* __restrict__ emb,
        const float* __restrict__ W_iou, const float* __restrict__ U_iou,
        const float* __restrict__ W_f,   const float* __restrict__ U_f,
        const float* __restrict__ b_Wiou, const float* __restrict__ b_Uiou,
        const float* __restrict__ b_Wf,   const float* __restrict__ b_Uf,
        bf16* __restrict__ Wcat, float* __restrict__ bias, bf16* __restrict__ emb16,
        bf16* __restrict__ leafH, float* __restrict__ leafC,
        bf16* __restrict__ H, float* __restrict__ c_buf, float* __restrict__ out)
{
    __shared__ __align__(16) char smem[38400];
    bf16* A0 = (bf16*)smem;
    bf16* A1 = (bf16*)(smem + 25600);
    cg::grid_group grid = cg::this_grid();
    const int blk = blockIdx.x, tid = threadIdx.x;
    const int gid = blk * 256 + tid;    // grid = 512 x 256

    // phase 0a: elementwise pack
    if (gid < 32768) {
        float4 v = *(const float4*)(emb + gid * 4);
        union { bf16 b[4]; uint2 u; } p;
        p.b[0] = (bf16)v.x; p.b[1] = (bf16)v.y; p.b[2] = (bf16)v.z; p.b[3] = (bf16)v.w;
        *(uint2*)(emb16 + gid * 4) = p.u;
    }
    if (gid < 15360) {
        int r = (gid * 4) / KDIM, k4 = (gid * 4) % KDIM;
        float4 v;
        if (k4 < 64) v = *(const float4*)((r < 192 ? W_iou + r * 64 : W_f + (r - 192) * 64) + k4);
        else         v = *(const float4*)((r < 192 ? U_iou + r * 128 : U_f + (r - 192) * 128) + (k4 - 64));
        union { bf16 b[4]; uint2 u; } p;
        p.b[0] = (bf16)(v.x * LOG2E); p.b[1] = (bf16)(v.y * LOG2E);
        p.b[2] = (bf16)(v.z * LOG2E); p.b[3] = (bf16)(v.w * LOG2E);
        *(uint2*)(Wcat + r * KDIM + k4) = p.u;
    }
    if (gid < RDIM)
        bias[gid] = ((gid < 192) ? (b_Wiou[gid] + b_Uiou[gid])
                                 : (b_Wf[gid - 192] + b_Uf[gid - 192])) * LOG2E;

    // phase 0b: leaf tables on blocks 0..31
    if (blk < 32) {
        bf16* Wl = (bf16*)smem;             // 192*72*2 = 27648 B
        bf16* Al = (bf16*)(smem + 27648);   // 64*72*2  =  9216 B
        const int v0 = blk * 64;
        for (int i = tid; i < 192 * 16; i += 256) {
            int r = i >> 4, k4 = (i & 15) << 2;
            float4 v = *(const float4*)(W_iou + r * 64 + k4);
            union { bf16 b[4]; uint2 u; } p;
            p.b[0] = (bf16)(v.x * LOG2E); p.b[1] = (bf16)(v.y * LOG2E);
            p.b[2] = (bf16)(v.z * LOG2E); p.b[3] = (bf16)(v.w * LOG2E);
            *(uint2*)&Wl[r * 72 + k4] = p.u;
        }
        for (int i = tid; i < 64 * 16; i += 256) {
            int row = i >> 4, k4 = (i & 15) << 2;
            float4 v = *(const float4*)(emb + (size_t)(v0 + row) * 64 + k4);
            union { bf16 b[4]; uint2 u; } p;
            p.b[0] = (bf16)v.x; p.b[1] = (bf16)v.y; p.b[2] = (bf16)v.z; p.b[3] = (bf16)v.w;
            *(uint2*)&Al[row * 72 + k4] = p.u;
        }
        __syncthreads();
        const int wave = tid >> 6, lane = tid & 63;
        const int l15 = lane & 15, quad = lane >> 4;
        const int jw = wave * 16, jb = jw + quad * 4;
        f32x4 acc[4][3];
#pragma unroll
        for (int t = 0; t < 4; t++)
#pragma unroll
            for (int g = 0; g < 3; g++) acc[t][g] = (f32x4){0.f, 0.f, 0.f, 0.f};
#pragma unroll
        for (int kb = 0; kb < 2; kb++) {
            bf16x8 wfrag[3], nfrag[4];
#pragma unroll
            for (int g = 0; g < 3; g++)
                wfrag[g] = *(const bf16x8*)(&Wl[(g * 64 + jw + l15) * 72 + kb * 32 + quad * 8]);
#pragma unroll
            for (int t = 0; t < 4; t++)
                nfrag[t] = *(const bf16x8*)(&Al[(t * 16 + l15) * 72 + kb * 32 + quad * 8]);
#pragma unroll
            for (int t = 0; t < 4; t++)
#pragma unroll
                for (int g = 0; g < 3; g++)
                    acc[t][g] = __builtin_amdgcn_mfma_f32_16x16x32_bf16(wfrag[g], nfrag[t], acc[t][g], 0, 0, 0);
        }
        float4 bW, bU_;
        bW = *(const float4*)(b_Wiou + jb);       bU_ = *(const float4*)(b_Uiou + jb);
        float4 bI = make_float4((bW.x + bU_.x) * LOG2E, (bW.y + bU_.y) * LOG2E,
                                (bW.z + bU_.z) * LOG2E, (bW.w + bU_.w) * LOG2E);
        bW = *(const float4*)(b_Wiou + 64 + jb);  bU_ = *(const float4*)(b_Uiou + 64 + jb);
        float4 bO = make_float4((bW.x + bU_.x) * LOG2E, (bW.y + bU_.y) * LOG2E,
                                (bW.z + bU_.z) * LOG2E, (bW.w + bU_.w) * LOG2E);
        bW = *(const float4*)(b_Wiou + 128 + jb); bU_ = *(const float4*)(b_Uiou + 128 + jb);
        float4 bU = make_float4((bW.x + bU_.x) * LOG2E, (bW.y + bU_.y) * LOG2E,
                                (bW.z + bU_.z) * LOG2E, (bW.w + bU_.w) * LOG2E);
        const float* pbI = &bI.x; const float* pbO = &bO.x; const float* pbU = &bU.x;
#pragma unroll
        for (int t = 0; t < 4; t++) {
            int v = v0 + t * 16 + l15;
            float4 c4; float* pc4 = &c4.x;
            union { bf16 h[4]; uint2 u; } hp;
#pragma unroll
            for (int r = 0; r < 4; r++) {
                float i_g = sig2(acc[t][0][r] + pbI[r]);
                float o_g = sig2(acc[t][1][r] + pbO[r]);
                float u_g = tanhf_(sig2(acc[t][2][r] + pbU[r]));
                float c = i_g * u_g;
                pc4[r] = c;
                hp.h[r] = (bf16)(o_g * tanhf_(c));
            }
            *(float4*)(leafC + (size_t)v * 64 + jb) = c4;
            *(uint2*)(leafH + (size_t)v * 64 + jb) = hp.u;
        }
    }
    grid.sync();

    // phase A: levels 16..10, 1024 subtrees = 512 blocks x 2
    subtree_body(16, blk * 2 + 0, 1, A0, A1, Wcat, bias, emb16, token_ids,
                 leafH, leafC, H, c_buf, tid);
    subtree_body(16, blk * 2 + 1, 1, A0, A1, Wcat, bias, emb16, token_ids,
                 leafH, leafC, H, c_buf, tid);
    grid.sync();

    // phase B: levels 9..3, 8 subtrees on blocks 0..7
    if (blk < 8)
        subtree_body(9, blk, 0, A0, A1, Wcat, bias, emb16, token_ids,
                     leafH, leafC, H, c_buf, tid);
    grid.sync();

    // phase C: levels 2..0 on block 0
    if (blk == 0)
        top3_body(Wcat, bias, emb16, token_ids, H, c_buf, out, tid);
}

extern "C" void kernel_launch(void* const* d_in, const int* in_sizes, int n_in,
                              void* d_out, int out_size, void* d_ws, size_t ws_size,
                              hipStream_t stream) {
    const int*   token_ids = (const int*)d_in[0];
    const float* emb       = (const float*)d_in[1];
    const float* W_iou     = (const float*)d_in[2];
    const float* b_Wiou    = (const float*)d_in[3];
    const float* U_iou     = (const float*)d_in[4];
    const float* b_Uiou    = (const float*)d_in[5];
    const float* W_f       = (const float*)d_in[6];
    const float* b_Wf      = (const float*)d_in[7];
    const float* U_f       = (const float*)d_in[8];
    const float* b_Uf      = (const float*)d_in[9];
    float* out = (float*)d_out;

    char* ws = (char*)d_ws;
    bf16*  Wcat  = (bf16*)ws;                               // 122880 B
    float* bias  = (float*)(ws + 122880);                   // -> 124160
    bf16*  emb16 = (bf16*)(ws + 124160);                    // -> 386304
    bf16*  leafH = (bf16*)(ws + 386304);                    // -> 648448
    float* leafC = (float*)(ws + 648448);                   // -> 1172736
    bf16*  H     = (bf16*)(ws + 1172736);                   // -> 34727040
    float* c_buf = (float*)(ws + 34727040);

    void* args[] = { (void*)&token_ids, (void*)&emb,
                     (void*)&W_iou, (void*)&U_iou, (void*)&W_f, (void*)&U_f,
                     (void*)&b_Wiou, (void*)&b_Uiou, (void*)&b_Wf, (void*)&b_Uf,
                     (void*)&Wcat, (void*)&bias, (void*)&emb16,
                     (void*)&leafH, (void*)&leafC,
                     (void*)&H, (void*)&c_buf, (void*)&out };
    hipError_t err = hipLaunchCooperativeKernel((void*)mega, dim3(512), dim3(256),
                                                args, 0, stream);
    if (err != hipSuccess) {
        // fallback: identical numerics via 4 regular dispatches
        prep_all<<<544, 256, 0, stream>>>(emb, W_iou, U_iou, W_f, U_f,
                                          b_Wiou, b_Uiou, b_Wf, b_Uf,
                                          Wcat, bias, emb16, leafH, leafC);
        subtree_kernel<<<1024, 256, 0, stream>>>(Wcat, bias, emb16, token_ids,
                                                 leafH, leafC, H, c_buf, 16, 1, 1);
        subtree_kernel<<<8, 256, 0, stream>>>(Wcat, bias, emb16, token_ids,
                                              leafH, leafC, H, c_buf, 9, 0, 1);
        tail3<<<1, 256, 0, stream>>>(Wcat, bias, emb16, token_ids, H, c_buf, out);
    }
}